// Round 2
// 213.943 us; speedup vs baseline: 1.0205x; 1.0205x over previous
//
#include <hip/hip_runtime.h>
#include <cmath>

#define BB 2
#define SS 2048
#define DD 1024
#define HH 16
#define HDIM 64
#define KDIM 1024
#define EPSF 1e-8f
// 0.125 (1/sqrt(HD)) * log2(e), folded into Q at projection time
#define QSCALE 0.18033688f

typedef __attribute__((ext_vector_type(8))) short bf16x8;
typedef __attribute__((ext_vector_type(4))) float f32x4;
typedef __attribute__((ext_vector_type(16))) float f32x16;

__device__ __forceinline__ ushort f2bf(float x) {
    unsigned u = __builtin_bit_cast(unsigned, x);
    u += 0x7FFFu + ((u >> 16) & 1u);   // RNE
    return (ushort)(u >> 16);
}

// pack two fp32 -> bf16x2 (truncation, 1 v_perm): low = a, high = b
__device__ __forceinline__ unsigned pack_bf16_trunc(float a, float b) {
    return __builtin_amdgcn_perm(__builtin_bit_cast(unsigned, b),
                                 __builtin_bit_cast(unsigned, a), 0x07060302u);
}

// raw v_exp_f32 (2^x): skips OCML range-guard code
__device__ __forceinline__ float exp2_fast(float x) {
    float r;
    asm("v_exp_f32 %0, %1" : "=v"(r) : "v"(x));
    return r;
}

__device__ __forceinline__ void gload_lds16(const ushort* g, ushort* l) {
    __builtin_amdgcn_global_load_lds(
        (const __attribute__((address_space(1))) unsigned*)g,
        (__attribute__((address_space(3))) unsigned*)l, 16, 0, 0);
}

// ---------------------------------------------------------------------------
// Fused fp32->bf16 conversion for hs + 4 weights (dsts contiguous in ws).
// ---------------------------------------------------------------------------
__global__ __launch_bounds__(256) void conv_all(
    const float* __restrict__ hs, const float* __restrict__ wq,
    const float* __restrict__ wk, const float* __restrict__ wv,
    const float* __restrict__ wo, ushort* __restrict__ dst)
{
    const int i = blockIdx.x * 256 + threadIdx.x;   // float4 group index
    const int HS4 = (BB * SS * DD) / 4;             // 1048576
    const int W4 = (DD * DD) / 4;                   // 262144
    const float* src;
    int off;
    if (i < HS4) { src = hs; off = i; }
    else {
        const int j = i - HS4;
        const int seg = j / W4;
        off = j - seg * W4;
        src = (seg == 0) ? wq : (seg == 1) ? wk : (seg == 2) ? wv : wo;
    }
    const float4 v = ((const float4*)src)[off];
    ushort4 o;
    o.x = f2bf(v.x); o.y = f2bf(v.y); o.z = f2bf(v.z); o.w = f2bf(v.w);
    ((ushort4*)dst)[i] = o;
}

// ---------------------------------------------------------------------------
// Kernel 1: fused QKV projection, bf16 MFMA (m97 structure).
// Q pre-scaled by QSCALE so attention softmax is a bare exp2.
// Q,K -> (B,H,S,HD) bf16; V -> (B,H,HD,S) bf16 (transposed).
// ---------------------------------------------------------------------------
__global__ __launch_bounds__(256) void gemm_qkv_mfma(
    const ushort* __restrict__ A,
    const ushort* __restrict__ Wq, const ushort* __restrict__ Wk,
    const ushort* __restrict__ Wv,
    const float* __restrict__ sinp, const float* __restrict__ cosp,
    ushort* __restrict__ Qb, ushort* __restrict__ Kb, ushort* __restrict__ Vtb)
{
    const int cb = blockIdx.y;
    const int z = cb >> 3;
    const int col0 = (cb & 7) * 128;
    const ushort* W = (z == 0) ? Wq : (z == 1) ? Wk : Wv;
    ushort* O = (z == 0) ? Qb : (z == 1) ? Kb : Vtb;
    const int row0 = blockIdx.x * 128;
    const float qs = (z == 0) ? QSCALE : 1.0f;

    __shared__ __align__(16) ushort As[128 * 32];
    __shared__ __align__(16) ushort Bs[128 * 32];

    const int tid = threadIdx.x;
    const int w = tid >> 6, lane = tid & 63;
    const int quad = lane >> 4, l15 = lane & 15;
    const int m_off = (w >> 1) * 64, n_off = (w & 1) * 64;

    f32x4 acc[4][4] = {};

    for (int k0 = 0; k0 < KDIM; k0 += 32) {
#pragma unroll
        for (int it = 0; it < 2; ++it) {
            const int L = (it * 4 + w) * 64 + lane;
            const int r = L >> 2, c8 = (L & 3) * 8;
            gload_lds16(A + (size_t)(row0 + r) * KDIM + k0 + c8, &As[L * 8]);
            gload_lds16(W + (size_t)(col0 + r) * KDIM + k0 + c8, &Bs[L * 8]);
        }
        __syncthreads();
        bf16x8 af[4], bfr[4];
#pragma unroll
        for (int i = 0; i < 4; ++i) {
            af[i]  = *(const bf16x8*)&As[(m_off + i * 16 + l15) * 32 + quad * 8];
            bfr[i] = *(const bf16x8*)&Bs[(n_off + i * 16 + l15) * 32 + quad * 8];
        }
#pragma unroll
        for (int i = 0; i < 4; ++i)
#pragma unroll
            for (int j = 0; j < 4; ++j)
                acc[i][j] = __builtin_amdgcn_mfma_f32_16x16x32_bf16(
                    af[i], bfr[j], acc[i][j], 0, 0, 0);
        __syncthreads();
    }

    const int b = (row0 + m_off) / SS;
#pragma unroll
    for (int mi = 0; mi < 4; ++mi) {
        const int mrow = row0 + m_off + mi * 16 + quad * 4;
#pragma unroll
        for (int ni = 0; ni < 4; ++ni) {
            const int c = col0 + n_off + ni * 16 + l15;
            const int h = c >> 6, e = c & 63;
            const int bh = b * HH + h;
            float outv[4];
#pragma unroll
            for (int r = 0; r < 4; ++r) {
                const int s = (mrow + r) & (SS - 1);
                const float sv = sinp[s * (HDIM / 2) + (e >> 1)];
                const float cv = cosp[s * (HDIM / 2) + (e >> 1)];
                const float v = acc[mi][ni][r];
                const float vp = __shfl_xor(v, 1);
                outv[r] = ((l15 & 1) ? (v * cv + vp * sv) : (v * cv - vp * sv)) * qs;
            }
            if (z < 2) {
#pragma unroll
                for (int r = 0; r < 4; ++r) {
                    const int s = (mrow + r) & (SS - 1);
                    const ushort mine = f2bf(outv[r]);
                    const ushort part = (ushort)__shfl_xor((int)mine, 1);
                    if (!(l15 & 1))
                        *(unsigned*)(O + ((size_t)(bh * SS + s)) * HDIM + e) =
                            (unsigned)mine | ((unsigned)part << 16);
                }
            } else {
                ushort4 pk;
                pk.x = f2bf(outv[0]); pk.y = f2bf(outv[1]);
                pk.z = f2bf(outv[2]); pk.w = f2bf(outv[3]);
                const int s0 = mrow & (SS - 1);
                *(ushort4*)(O + ((size_t)(bh * HDIM + e)) * SS + s0) = pk;
            }
        }
    }
}

// ---------------------------------------------------------------------------
// Kernel 2: flash attention, 32x32x16 bf16 MFMA, S^T formulation, in-block
// key-split, XOR-swizzled LDS.
// Round-change vs 218us version:
//   * 64-key tiles, TRUE ping-pong double buffer in the SAME 32 KB LDS:
//     one barrier per tile, LDS writes of tile t+1 overlap compute of tile t
//     (old code had write -> barrier -> write -> barrier fully serialized).
//   * P^T half-swap via v_permlane32_swap_b32 (2 instrs/k-step) instead of
//     4x __shfl_xor + 4x cndmask.
//   * s_setprio(1) around the MFMA clusters (T5, +4-7% measured on attn).
//   * XCD-bijective block swizzle: 128 consecutive (bh,qblk) blocks per XCD
//     -> each XCD touches only 4 heads' K/V (2 MB, L2-resident).
// ---------------------------------------------------------------------------
__global__ __launch_bounds__(256) void attn_mfma(
    const ushort* __restrict__ Qb, const ushort* __restrict__ Kb,
    const ushort* __restrict__ Vtb, ushort* __restrict__ ctx)
{
    // XCD swizzle: grid 1024 = 8 XCDs x 128; dispatch round-robins XCDs, so
    // wg&7 = xcd, contiguous lin chunk per XCD => 4 heads per XCD.
    const int wg  = blockIdx.x;
    const int lin = (wg & 7) * 128 + (wg >> 3);
    const int bh   = lin >> 5;          // 0..31
    const int qblk = lin & 31;          // 0..31
    const int b = bh / HH, h = bh % HH;
    const int q0 = qblk * 64;
    const int tid = threadIdx.x;
    const int w = tid >> 6;
    const int lane = tid & 63;
    const int l31 = lane & 31;
    const int g = lane >> 5;
    const int strip = w >> 1;     // q-strip: waves {0,1} -> 0, {2,3} -> 1
    const int phase = w & 1;      // key phase: low/high 32 keys of the tile

    // [buf][K=0/V=1][hf][row][32] ; K: hf = d-half, row = key (0..63)
    //                              V: hf = key-half, row = d (0..63). 32 KB.
    __shared__ __align__(16) ushort kvb[2][2][2][64][32];

    const ushort* Qh = Qb  + (size_t)bh * SS * HDIM;
    const ushort* Kh = Kb  + (size_t)bh * SS * HDIM;
    const ushort* Vh = Vtb + (size_t)bh * HDIM * SS;

    // Q B-fragments (n = l31 = q-row, k = d)
    const int qrow = q0 + strip * 32 + l31;
    bf16x8 qf[4];
#pragma unroll
    for (int ks = 0; ks < 4; ++ks)
        qf[ks] = *(const bf16x8*)(Qh + (size_t)qrow * HDIM + ks * 16 + g * 8);

    f32x16 cacc[2] = {};
    float lsum = 0.f;

    const int lr = lane >> 2;               // staging row-in-16
    const int c16 = lane & 3;               // 16-B chunk index
    const int lc = c16 * 8;                 // ushort col in global
    const int swc = (c16 ^ (lr & 3)) * 8;   // swizzled LDS chunk
    const int srow = w * 16 + lr;           // staging row 0..63

    // staging registers for ONE 64-key tile (K: 2 d-halves, V: 2 key-halves)
    uint4 rk0, rk1, rv0, rv1;

#define LOAD_STAGE(K0)                                                        \
    do {                                                                      \
        const ushort* Kp = Kh + (size_t)((K0) + srow) * HDIM + lc;            \
        const ushort* Vp = Vh + (size_t)srow * SS + (K0) + lc;                \
        rk0 = *(const uint4*)(Kp);                                            \
        rk1 = *(const uint4*)(Kp + 32);                                       \
        rv0 = *(const uint4*)(Vp);                                            \
        rv1 = *(const uint4*)(Vp + 32);                                       \
    } while (0)

#define WRITE_STAGE(bufi)                                                     \
    do {                                                                      \
        *(uint4*)&kvb[bufi][0][0][srow][swc] = rk0;                           \
        *(uint4*)&kvb[bufi][0][1][srow][swc] = rk1;                           \
        *(uint4*)&kvb[bufi][1][0][srow][swc] = rv0;                           \
        *(uint4*)&kvb[bufi][1][1][srow][swc] = rv1;                           \
    } while (0)

    const int NT = SS / 64;                 // 32 tiles

    LOAD_STAGE(0);
    WRITE_STAGE(0);
    LOAD_STAGE(64);                         // regs now hold tile 1

    for (int t = 0; t < NT; ++t) {
        __syncthreads();      // buf[t&1] writes visible; buf[t&1^1] readers done
        const int cur = t & 1;

        // ---- K fragment reads FIRST (so their lgkm wait excludes writes) ----
        bf16x8 kf[4];
#pragma unroll
        for (int ks = 0; ks < 4; ++ks)
            kf[ks] = *(const bf16x8*)&kvb[cur][0][ks >> 1]
                [phase * 32 + l31][(((ks & 1) * 2 + g) ^ (l31 & 3)) * 8];

        // ---- overlap: write tile t+1 into the other buffer, prefetch t+2 ----
        if (t + 1 < NT) WRITE_STAGE(cur ^ 1);
        if (t + 2 < NT) LOAD_STAGE((t + 2) * 64);

        // ---- S^T = K . Q^T on my 32-key half ----
        f32x16 sacc = {};
        __builtin_amdgcn_s_setprio(1);
#pragma unroll
        for (int ks = 0; ks < 4; ++ks)
            sacc = __builtin_amdgcn_mfma_f32_32x32x16_bf16(
                kf[ks], qf[ks], sacc, 0, 0, 0);
        __builtin_amdgcn_s_setprio(0);

        // ---- shift-free softmax + pack P^T pairs ----
        unsigned pk[8];
#pragma unroll
        for (int i = 0; i < 8; ++i) {
            const float pa = exp2_fast(sacc[2 * i]);
            const float pb = exp2_fast(sacc[2 * i + 1]);
            lsum += pa + pb;
            pk[i] = pack_bf16_trunc(pa, pb);
        }

        // ---- ctx^T += V^T . P^T (permlane32_swap builds B-fragments) ----
#pragma unroll
        for (int ks = 0; ks < 2; ++ks) {
            const int bq = ks * 4;
            unsigned a0 = pk[bq + 0], a1 = pk[bq + 1];
            unsigned b0 = pk[bq + 2], b1 = pk[bq + 3];
            // swap my hi-32-lane half of a* with partner's lo half of b*:
            // new a = {a.lo | b.lo}, new b = {a.hi | b.hi} across halves
            asm("v_permlane32_swap_b32 %0, %1" : "+v"(a0), "+v"(b0));
            asm("v_permlane32_swap_b32 %0, %1" : "+v"(a1), "+v"(b1));
            union { unsigned u[4]; bf16x8 v; } pf;
            pf.u[0] = a0; pf.u[1] = a1; pf.u[2] = b0; pf.u[3] = b1;
            __builtin_amdgcn_s_setprio(1);
#pragma unroll
            for (int dt = 0; dt < 2; ++dt) {
                const bf16x8 vf = *(const bf16x8*)&kvb[cur][1][phase]
                    [dt * 32 + l31][((ks * 2 + g) ^ (l31 & 3)) * 8];
                cacc[dt] = __builtin_amdgcn_mfma_f32_32x32x16_bf16(
                    vf, pf.v, cacc[dt], 0, 0, 0);
            }
            __builtin_amdgcn_s_setprio(0);
        }
    }

    // within-wave: partner half holds the other half of each 32-key chunk
    lsum += __shfl_xor(lsum, 32);

    // ---- strip merge: phase-1 wave hands partials to phase-0 wave ----
    __syncthreads();
    float* mlds = (float*)kvb;
    const int mbase = strip * 2112 + lane * 33;   // stride 33: conflict-free
    if (phase == 1) {
#pragma unroll
        for (int dt = 0; dt < 2; ++dt)
#pragma unroll
            for (int i = 0; i < 16; ++i) mlds[mbase + dt * 16 + i] = cacc[dt][i];
        mlds[mbase + 32] = lsum;
    }
    __syncthreads();
    if (phase == 0) {
#pragma unroll
        for (int dt = 0; dt < 2; ++dt)
#pragma unroll
            for (int i = 0; i < 16; ++i) cacc[dt][i] += mlds[mbase + dt * 16 + i];
        lsum += mlds[mbase + 32];
        const float inv = 1.f / lsum;

        // epilogue: C-layout col = l31 = q, row = (r&3)+8*(r>>2)+4g = d-local
        const size_t obase = ((size_t)(b * SS + qrow)) * DD + h * HDIM;
#pragma unroll
        for (int dt = 0; dt < 2; ++dt)
#pragma unroll
            for (int t = 0; t < 4; ++t) {
                ushort4 o;
                o.x = f2bf(cacc[dt][t * 4 + 0] * inv);
                o.y = f2bf(cacc[dt][t * 4 + 1] * inv);
                o.z = f2bf(cacc[dt][t * 4 + 2] * inv);
                o.w = f2bf(cacc[dt][t * 4 + 3] * inv);
                *(ushort4*)(ctx + obase + dt * 32 + t * 8 + g * 4) = o;
            }
    }
#undef LOAD_STAGE
#undef WRITE_STAGE
}

// ---------------------------------------------------------------------------
// Kernel 3: output projection, bf16 MFMA, 128x64 tile (512 blocks = 2/CU),
// + bias, fp32 out (B*S, D).
// ---------------------------------------------------------------------------
__global__ __launch_bounds__(256) void gemm_out_mfma(
    const ushort* __restrict__ A, const ushort* __restrict__ W,
    const float* __restrict__ bias, float* __restrict__ Out)
{
    const int row0 = blockIdx.x * 128;
    const int col0 = blockIdx.y * 64;

    __shared__ __align__(16) ushort As[128 * 32];
    __shared__ __align__(16) ushort Bs[64 * 32];

    const int tid = threadIdx.x;
    const int w = tid >> 6, lane = tid & 63;
    const int quad = lane >> 4, l15 = lane & 15;
    const int m_off = (w >> 1) * 64, n_off = (w & 1) * 32;

    f32x4 acc[4][2] = {};

    for (int k0 = 0; k0 < KDIM; k0 += 32) {
#pragma unroll
        for (int it = 0; it < 2; ++it) {
            const int L = (it * 4 + w) * 64 + lane;
            const int r = L >> 2, c8 = (L & 3) * 8;
            gload_lds16(A + (size_t)(row0 + r) * KDIM + k0 + c8, &As[L * 8]);
        }
        {
            const int L = w * 64 + lane;
            const int r = L >> 2, c8 = (L & 3) * 8;
            gload_lds16(W + (size_t)(col0 + r) * KDIM + k0 + c8, &Bs[L * 8]);
        }
        __syncthreads();
        bf16x8 af[4], bfr[2];
#pragma unroll
        for (int i = 0; i < 4; ++i)
            af[i] = *(const bf16x8*)&As[(m_off + i * 16 + l15) * 32 + quad * 8];
#pragma unroll
        for (int j = 0; j < 2; ++j)
            bfr[j] = *(const bf16x8*)&Bs[(n_off + j * 16 + l15) * 32 + quad * 8];
#pragma unroll
        for (int i = 0; i < 4; ++i)
#pragma unroll
            for (int j = 0; j < 2; ++j)
                acc[i][j] = __builtin_amdgcn_mfma_f32_16x16x32_bf16(
                    af[i], bfr[j], acc[i][j], 0, 0, 0);
        __syncthreads();
    }

#pragma unroll
    for (int mi = 0; mi < 4; ++mi) {
        const int mrow = row0 + m_off + mi * 16 + quad * 4;
#pragma unroll
        for (int ni = 0; ni < 2; ++ni) {
            const int c = col0 + n_off + ni * 16 + l15;
            const float bv = bias[c];
#pragma unroll
            for (int r = 0; r < 4; ++r)
                Out[(size_t)(mrow + r) * DD + c] = acc[mi][ni][r] + bv;
        }
    }
}

// ---------------------------------------------------------------------------
// Kernel 4: residual add + RMSNorm. One block per token.
// ---------------------------------------------------------------------------
__global__ __launch_bounds__(256) void resid_rmsnorm(
    const float* __restrict__ proj, const float* __restrict__ hs,
    const float* __restrict__ scale, float* __restrict__ out)
{
    const int t = blockIdx.x;
    const int tid = threadIdx.x;
    const size_t base = (size_t)t * DD + tid * 4;

    const float4 p4 = *(const float4*)(proj + base);
    const float4 h4 = *(const float4*)(hs + base);
    float x0 = p4.x + h4.x, x1 = p4.y + h4.y, x2 = p4.z + h4.z, x3 = p4.w + h4.w;
    float ss = x0 * x0 + x1 * x1 + x2 * x2 + x3 * x3;

#pragma unroll
    for (int off = 1; off < 64; off <<= 1) ss += __shfl_xor(ss, off);

    __shared__ float wsum[4];
    if ((tid & 63) == 0) wsum[tid >> 6] = ss;
    __syncthreads();
    const float total = wsum[0] + wsum[1] + wsum[2] + wsum[3];
    const float inv = 1.f / (sqrtf(total * (1.f / DD)) + EPSF);

    const float4 s4 = *(const float4*)(scale + tid * 4);
    float4 o;
    o.x = s4.x * x0 * inv;
    o.y = s4.y * x1 * inv;
    o.z = s4.z * x2 * inv;
    o.w = s4.w * x3 * inv;
    *(float4*)(out + base) = o;
}

// ---------------------------------------------------------------------------
extern "C" void kernel_launch(void* const* d_in, const int* in_sizes, int n_in,
                              void* d_out, int out_size, void* d_ws, size_t ws_size,
                              hipStream_t stream) {
    const float* hs    = (const float*)d_in[0];
    const float* sinp  = (const float*)d_in[1];
    const float* cosp  = (const float*)d_in[2];
    const float* wq    = (const float*)d_in[3];
    const float* wk    = (const float*)d_in[4];
    const float* wv    = (const float*)d_in[5];
    const float* wo    = (const float*)d_in[6];
    const float* bo    = (const float*)d_in[7];
    const float* scale = (const float*)d_in[8];
    float* out = (float*)d_out;

    unsigned char* wsb = (unsigned char*)d_ws;
    const size_t MAT = (size_t)BB * SS * DD;
    const size_t WN  = (size_t)DD * DD;
    ushort* Abf = (ushort*)wsb;           // contiguous: Abf, Wqb, Wkb, Wvb, Wob
    ushort* Wqb = Abf + MAT;
    ushort* Wkb = Wqb + WN;
    ushort* Wvb = Wkb + WN;
    ushort* Wob = Wvb + WN;
    ushort* Qb  = Wob + WN;
    ushort* Kb  = Qb + MAT;
    ushort* Vtb = Kb + MAT;
    ushort* ctxb = Vtb + MAT;
    float* proj = (float*)(ctxb + MAT);

    const int nconv4 = (int)((MAT + 4 * WN) / 4);    // 2M float4 groups
    conv_all<<<dim3(nconv4 / 256), 256, 0, stream>>>(hs, wq, wk, wv, wo, Abf);

    gemm_qkv_mfma<<<dim3(32, 24), 256, 0, stream>>>(Abf, Wqb, Wkb, Wvb,
                                                    sinp, cosp, Qb, Kb, Vtb);
    attn_mfma<<<dim3(32 * BB * HH), 256, 0, stream>>>(Qb, Kb, Vtb, ctxb);
    gemm_out_mfma<<<dim3(32, 16), 256, 0, stream>>>(ctxb, Wob, bo, proj);
    resid_rmsnorm<<<dim3(BB * SS), 256, 0, stream>>>(proj, hs, scale, out);
}

// Round 3
// 208.138 us; speedup vs baseline: 1.0490x; 1.0279x over previous
//
#include <hip/hip_runtime.h>
#include <cmath>

#define BB 2
#define SS 2048
#define DD 1024
#define HH 16
#define HDIM 64
#define KDIM 1024
#define EPSF 1e-8f
// 0.125 (1/sqrt(HD)) * log2(e), folded into Q at projection time
#define QSCALE 0.18033688f

typedef __attribute__((ext_vector_type(8))) short bf16x8;
typedef __attribute__((ext_vector_type(4))) float f32x4;
typedef __attribute__((ext_vector_type(16))) float f32x16;

__device__ __forceinline__ ushort f2bf(float x) {
    unsigned u = __builtin_bit_cast(unsigned, x);
    u += 0x7FFFu + ((u >> 16) & 1u);   // RNE
    return (ushort)(u >> 16);
}

// pack two fp32 -> bf16x2 (truncation, 1 v_perm): low = a, high = b
__device__ __forceinline__ unsigned pack_bf16_trunc(float a, float b) {
    return __builtin_amdgcn_perm(__builtin_bit_cast(unsigned, b),
                                 __builtin_bit_cast(unsigned, a), 0x07060302u);
}

// raw v_exp_f32 (2^x): skips OCML range-guard code
__device__ __forceinline__ float exp2_fast(float x) {
    float r;
    asm("v_exp_f32 %0, %1" : "=v"(r) : "v"(x));
    return r;
}

__device__ __forceinline__ void gload_lds16(const ushort* g, ushort* l) {
    __builtin_amdgcn_global_load_lds(
        (const __attribute__((address_space(1))) unsigned*)g,
        (__attribute__((address_space(3))) unsigned*)l, 16, 0, 0);
}

// ---------------------------------------------------------------------------
// Fused fp32->bf16 conversion for hs + 4 weights (dsts contiguous in ws).
// ---------------------------------------------------------------------------
__global__ __launch_bounds__(256) void conv_all(
    const float* __restrict__ hs, const float* __restrict__ wq,
    const float* __restrict__ wk, const float* __restrict__ wv,
    const float* __restrict__ wo, ushort* __restrict__ dst)
{
    const int i = blockIdx.x * 256 + threadIdx.x;   // float4 group index
    const int HS4 = (BB * SS * DD) / 4;             // 1048576
    const int W4 = (DD * DD) / 4;                   // 262144
    const float* src;
    int off;
    if (i < HS4) { src = hs; off = i; }
    else {
        const int j = i - HS4;
        const int seg = j / W4;
        off = j - seg * W4;
        src = (seg == 0) ? wq : (seg == 1) ? wk : (seg == 2) ? wv : wo;
    }
    const float4 v = ((const float4*)src)[off];
    ushort4 o;
    o.x = f2bf(v.x); o.y = f2bf(v.y); o.z = f2bf(v.z); o.w = f2bf(v.w);
    ((ushort4*)dst)[i] = o;
}

// ---------------------------------------------------------------------------
// Kernel 1: fused QKV projection, bf16 MFMA (m97 structure).
// Q pre-scaled by QSCALE so attention softmax is a bare exp2.
// Q,K -> (B,H,S,HD) bf16; V -> (B,H,HD,S) bf16 (transposed).
// ---------------------------------------------------------------------------
__global__ __launch_bounds__(256) void gemm_qkv_mfma(
    const ushort* __restrict__ A,
    const ushort* __restrict__ Wq, const ushort* __restrict__ Wk,
    const ushort* __restrict__ Wv,
    const float* __restrict__ sinp, const float* __restrict__ cosp,
    ushort* __restrict__ Qb, ushort* __restrict__ Kb, ushort* __restrict__ Vtb)
{
    const int cb = blockIdx.y;
    const int z = cb >> 3;
    const int col0 = (cb & 7) * 128;
    const ushort* W = (z == 0) ? Wq : (z == 1) ? Wk : Wv;
    ushort* O = (z == 0) ? Qb : (z == 1) ? Kb : Vtb;
    const int row0 = blockIdx.x * 128;
    const float qs = (z == 0) ? QSCALE : 1.0f;

    __shared__ __align__(16) ushort As[128 * 32];
    __shared__ __align__(16) ushort Bs[128 * 32];

    const int tid = threadIdx.x;
    const int w = tid >> 6, lane = tid & 63;
    const int quad = lane >> 4, l15 = lane & 15;
    const int m_off = (w >> 1) * 64, n_off = (w & 1) * 64;

    f32x4 acc[4][4] = {};

    for (int k0 = 0; k0 < KDIM; k0 += 32) {
#pragma unroll
        for (int it = 0; it < 2; ++it) {
            const int L = (it * 4 + w) * 64 + lane;
            const int r = L >> 2, c8 = (L & 3) * 8;
            gload_lds16(A + (size_t)(row0 + r) * KDIM + k0 + c8, &As[L * 8]);
            gload_lds16(W + (size_t)(col0 + r) * KDIM + k0 + c8, &Bs[L * 8]);
        }
        __syncthreads();
        bf16x8 af[4], bfr[4];
#pragma unroll
        for (int i = 0; i < 4; ++i) {
            af[i]  = *(const bf16x8*)&As[(m_off + i * 16 + l15) * 32 + quad * 8];
            bfr[i] = *(const bf16x8*)&Bs[(n_off + i * 16 + l15) * 32 + quad * 8];
        }
#pragma unroll
        for (int i = 0; i < 4; ++i)
#pragma unroll
            for (int j = 0; j < 4; ++j)
                acc[i][j] = __builtin_amdgcn_mfma_f32_16x16x32_bf16(
                    af[i], bfr[j], acc[i][j], 0, 0, 0);
        __syncthreads();
    }

    const int b = (row0 + m_off) / SS;
#pragma unroll
    for (int mi = 0; mi < 4; ++mi) {
        const int mrow = row0 + m_off + mi * 16 + quad * 4;
#pragma unroll
        for (int ni = 0; ni < 4; ++ni) {
            const int c = col0 + n_off + ni * 16 + l15;
            const int h = c >> 6, e = c & 63;
            const int bh = b * HH + h;
            float outv[4];
#pragma unroll
            for (int r = 0; r < 4; ++r) {
                const int s = (mrow + r) & (SS - 1);
                const float sv = sinp[s * (HDIM / 2) + (e >> 1)];
                const float cv = cosp[s * (HDIM / 2) + (e >> 1)];
                const float v = acc[mi][ni][r];
                const float vp = __shfl_xor(v, 1);
                outv[r] = ((l15 & 1) ? (v * cv + vp * sv) : (v * cv - vp * sv)) * qs;
            }
            if (z < 2) {
#pragma unroll
                for (int r = 0; r < 4; ++r) {
                    const int s = (mrow + r) & (SS - 1);
                    const ushort mine = f2bf(outv[r]);
                    const ushort part = (ushort)__shfl_xor((int)mine, 1);
                    if (!(l15 & 1))
                        *(unsigned*)(O + ((size_t)(bh * SS + s)) * HDIM + e) =
                            (unsigned)mine | ((unsigned)part << 16);
                }
            } else {
                ushort4 pk;
                pk.x = f2bf(outv[0]); pk.y = f2bf(outv[1]);
                pk.z = f2bf(outv[2]); pk.w = f2bf(outv[3]);
                const int s0 = mrow & (SS - 1);
                *(ushort4*)(O + ((size_t)(bh * HDIM + e)) * SS + s0) = pk;
            }
        }
    }
}

// ---------------------------------------------------------------------------
// Kernel 2: flash attention, 32x32x16 bf16 MFMA, S^T formulation, in-block
// key-split, XOR-swizzled LDS, single-barrier ping-pong double buffer.
// Round-change vs 70.6us version:
//   * Bank-conflict fix: swizzle f(row) changed (row&3) -> ((row>>1)&3).
//     Row stride is 64B = 16 banks, so bank-group = 4*(row&1) + chunk.
//     Old swizzle had period 4 in row -> rows {0,4,8,12} of a 16-lane
//     quarter-wave hit the SAME 4-bank group = 4-way conflict (1.58x, m136).
//     New swizzle cycles all 8 bank-groups over 8 consecutive rows -> 2-way
//     (free). Write side stays 2-way under the same involution.
//     Predicted: SQ_LDS_BANK_CONFLICT 1.26e7 -> ~2e6.
//   * lsum split into 4 partials (was a 16-deep dependent add chain/tile).
// ---------------------------------------------------------------------------
__global__ __launch_bounds__(256) void attn_mfma(
    const ushort* __restrict__ Qb, const ushort* __restrict__ Kb,
    const ushort* __restrict__ Vtb, ushort* __restrict__ ctx)
{
    // XCD swizzle: grid 1024 = 8 XCDs x 128; dispatch round-robins XCDs, so
    // wg&7 = xcd, contiguous lin chunk per XCD => 4 heads per XCD (2 MB K/V,
    // L2-resident; verified R2: FETCH 69.7 MB -> 12.3 MB).
    const int wg  = blockIdx.x;
    const int lin = (wg & 7) * 128 + (wg >> 3);
    const int bh   = lin >> 5;          // 0..31
    const int qblk = lin & 31;          // 0..31
    const int b = bh / HH, h = bh % HH;
    const int q0 = qblk * 64;
    const int tid = threadIdx.x;
    const int w = tid >> 6;
    const int lane = tid & 63;
    const int l31 = lane & 31;
    const int g = lane >> 5;
    const int strip = w >> 1;     // q-strip: waves {0,1} -> 0, {2,3} -> 1
    const int phase = w & 1;      // key phase: low/high 32 keys of the tile

    // [buf][K=0/V=1][hf][row][32] ; K: hf = d-half, row = key (0..63)
    //                              V: hf = key-half, row = d (0..63). 32 KB.
    __shared__ __align__(16) ushort kvb[2][2][2][64][32];

    const ushort* Qh = Qb  + (size_t)bh * SS * HDIM;
    const ushort* Kh = Kb  + (size_t)bh * SS * HDIM;
    const ushort* Vh = Vtb + (size_t)bh * HDIM * SS;

    // Q B-fragments (n = l31 = q-row, k = d)
    const int qrow = q0 + strip * 32 + l31;
    bf16x8 qf[4];
#pragma unroll
    for (int ks = 0; ks < 4; ++ks)
        qf[ks] = *(const bf16x8*)(Qh + (size_t)qrow * HDIM + ks * 16 + g * 8);

    f32x16 cacc[2] = {};
    float ls0 = 0.f, ls1 = 0.f, ls2 = 0.f, ls3 = 0.f;

    const int lr = lane >> 2;               // staging row-in-16
    const int c16 = lane & 3;               // 16-B chunk index
    const int lc = c16 * 8;                 // ushort col in global
    const int swc = (c16 ^ ((lr >> 1) & 3)) * 8;   // swizzled LDS chunk
    const int srow = w * 16 + lr;           // staging row 0..63
    const int rsw = (l31 >> 1) & 3;         // read-side swizzle term

    // staging registers for ONE 64-key tile (K: 2 d-halves, V: 2 key-halves)
    uint4 rk0, rk1, rv0, rv1;

#define LOAD_STAGE(K0)                                                        \
    do {                                                                      \
        const ushort* Kp = Kh + (size_t)((K0) + srow) * HDIM + lc;            \
        const ushort* Vp = Vh + (size_t)srow * SS + (K0) + lc;                \
        rk0 = *(const uint4*)(Kp);                                            \
        rk1 = *(const uint4*)(Kp + 32);                                       \
        rv0 = *(const uint4*)(Vp);                                            \
        rv1 = *(const uint4*)(Vp + 32);                                       \
    } while (0)

#define WRITE_STAGE(bufi)                                                     \
    do {                                                                      \
        *(uint4*)&kvb[bufi][0][0][srow][swc] = rk0;                           \
        *(uint4*)&kvb[bufi][0][1][srow][swc] = rk1;                           \
        *(uint4*)&kvb[bufi][1][0][srow][swc] = rv0;                           \
        *(uint4*)&kvb[bufi][1][1][srow][swc] = rv1;                           \
    } while (0)

    const int NT = SS / 64;                 // 32 tiles

    LOAD_STAGE(0);
    WRITE_STAGE(0);
    LOAD_STAGE(64);                         // regs now hold tile 1

    for (int t = 0; t < NT; ++t) {
        __syncthreads();      // buf[t&1] writes visible; buf[t&1^1] readers done
        const int cur = t & 1;

        // ---- K fragment reads FIRST (so their lgkm wait excludes writes) ----
        bf16x8 kf[4];
#pragma unroll
        for (int ks = 0; ks < 4; ++ks)
            kf[ks] = *(const bf16x8*)&kvb[cur][0][ks >> 1]
                [phase * 32 + l31][(((ks & 1) * 2 + g) ^ rsw) * 8];

        // ---- overlap: write tile t+1 into the other buffer, prefetch t+2 ----
        if (t + 1 < NT) WRITE_STAGE(cur ^ 1);
        if (t + 2 < NT) LOAD_STAGE((t + 2) * 64);

        // ---- S^T = K . Q^T on my 32-key half ----
        f32x16 sacc = {};
        __builtin_amdgcn_s_setprio(1);
#pragma unroll
        for (int ks = 0; ks < 4; ++ks)
            sacc = __builtin_amdgcn_mfma_f32_32x32x16_bf16(
                kf[ks], qf[ks], sacc, 0, 0, 0);
        __builtin_amdgcn_s_setprio(0);

        // ---- shift-free softmax + pack P^T pairs (4 partial lsum chains) ----
        unsigned pk[8];
#pragma unroll
        for (int i = 0; i < 8; ++i) {
            const float pa = exp2_fast(sacc[2 * i]);
            const float pb = exp2_fast(sacc[2 * i + 1]);
            if ((i & 3) == 0) ls0 += pa + pb;
            else if ((i & 3) == 1) ls1 += pa + pb;
            else if ((i & 3) == 2) ls2 += pa + pb;
            else ls3 += pa + pb;
            pk[i] = pack_bf16_trunc(pa, pb);
        }

        // ---- ctx^T += V^T . P^T (permlane32_swap builds B-fragments) ----
#pragma unroll
        for (int ks = 0; ks < 2; ++ks) {
            const int bq = ks * 4;
            unsigned a0 = pk[bq + 0], a1 = pk[bq + 1];
            unsigned b0 = pk[bq + 2], b1 = pk[bq + 3];
            // swap my hi-32-lane half of a* with partner's lo half of b*:
            // new a = {a.lo | b.lo}, new b = {a.hi | b.hi} across halves
            asm("v_permlane32_swap_b32 %0, %1" : "+v"(a0), "+v"(b0));
            asm("v_permlane32_swap_b32 %0, %1" : "+v"(a1), "+v"(b1));
            union { unsigned u[4]; bf16x8 v; } pf;
            pf.u[0] = a0; pf.u[1] = a1; pf.u[2] = b0; pf.u[3] = b1;
            __builtin_amdgcn_s_setprio(1);
#pragma unroll
            for (int dt = 0; dt < 2; ++dt) {
                const bf16x8 vf = *(const bf16x8*)&kvb[cur][1][phase]
                    [dt * 32 + l31][((ks * 2 + g) ^ rsw) * 8];
                cacc[dt] = __builtin_amdgcn_mfma_f32_32x32x16_bf16(
                    vf, pf.v, cacc[dt], 0, 0, 0);
            }
            __builtin_amdgcn_s_setprio(0);
        }
    }

    float lsum = (ls0 + ls1) + (ls2 + ls3);
    // within-wave: partner half holds the other half of each 32-key chunk
    lsum += __shfl_xor(lsum, 32);

    // ---- strip merge: phase-1 wave hands partials to phase-0 wave ----
    __syncthreads();
    float* mlds = (float*)kvb;
    const int mbase = strip * 2112 + lane * 33;   // stride 33: conflict-free
    if (phase == 1) {
#pragma unroll
        for (int dt = 0; dt < 2; ++dt)
#pragma unroll
            for (int i = 0; i < 16; ++i) mlds[mbase + dt * 16 + i] = cacc[dt][i];
        mlds[mbase + 32] = lsum;
    }
    __syncthreads();
    if (phase == 0) {
#pragma unroll
        for (int dt = 0; dt < 2; ++dt)
#pragma unroll
            for (int i = 0; i < 16; ++i) cacc[dt][i] += mlds[mbase + dt * 16 + i];
        lsum += mlds[mbase + 32];
        const float inv = 1.f / lsum;

        // epilogue: C-layout col = l31 = q, row = (r&3)+8*(r>>2)+4g = d-local
        const size_t obase = ((size_t)(b * SS + qrow)) * DD + h * HDIM;
#pragma unroll
        for (int dt = 0; dt < 2; ++dt)
#pragma unroll
            for (int t = 0; t < 4; ++t) {
                ushort4 o;
                o.x = f2bf(cacc[dt][t * 4 + 0] * inv);
                o.y = f2bf(cacc[dt][t * 4 + 1] * inv);
                o.z = f2bf(cacc[dt][t * 4 + 2] * inv);
                o.w = f2bf(cacc[dt][t * 4 + 3] * inv);
                *(ushort4*)(ctx + obase + dt * 32 + t * 8 + g * 4) = o;
            }
    }
#undef LOAD_STAGE
#undef WRITE_STAGE
}

// ---------------------------------------------------------------------------
// Kernel 3: output projection, bf16 MFMA, 128x64 tile (512 blocks = 2/CU),
// + bias, fp32 out (B*S, D).
// ---------------------------------------------------------------------------
__global__ __launch_bounds__(256) void gemm_out_mfma(
    const ushort* __restrict__ A, const ushort* __restrict__ W,
    const float* __restrict__ bias, float* __restrict__ Out)
{
    const int row0 = blockIdx.x * 128;
    const int col0 = blockIdx.y * 64;

    __shared__ __align__(16) ushort As[128 * 32];
    __shared__ __align__(16) ushort Bs[64 * 32];

    const int tid = threadIdx.x;
    const int w = tid >> 6, lane = tid & 63;
    const int quad = lane >> 4, l15 = lane & 15;
    const int m_off = (w >> 1) * 64, n_off = (w & 1) * 32;

    f32x4 acc[4][2] = {};

    for (int k0 = 0; k0 < KDIM; k0 += 32) {
#pragma unroll
        for (int it = 0; it < 2; ++it) {
            const int L = (it * 4 + w) * 64 + lane;
            const int r = L >> 2, c8 = (L & 3) * 8;
            gload_lds16(A + (size_t)(row0 + r) * KDIM + k0 + c8, &As[L * 8]);
        }
        {
            const int L = w * 64 + lane;
            const int r = L >> 2, c8 = (L & 3) * 8;
            gload_lds16(W + (size_t)(col0 + r) * KDIM + k0 + c8, &Bs[L * 8]);
        }
        __syncthreads();
        bf16x8 af[4], bfr[2];
#pragma unroll
        for (int i = 0; i < 4; ++i)
            af[i] = *(const bf16x8*)&As[(m_off + i * 16 + l15) * 32 + quad * 8];
#pragma unroll
        for (int j = 0; j < 2; ++j)
            bfr[j] = *(const bf16x8*)&Bs[(n_off + j * 16 + l15) * 32 + quad * 8];
#pragma unroll
        for (int i = 0; i < 4; ++i)
#pragma unroll
            for (int j = 0; j < 2; ++j)
                acc[i][j] = __builtin_amdgcn_mfma_f32_16x16x32_bf16(
                    af[i], bfr[j], acc[i][j], 0, 0, 0);
        __syncthreads();
    }

#pragma unroll
    for (int mi = 0; mi < 4; ++mi) {
        const int mrow = row0 + m_off + mi * 16 + quad * 4;
#pragma unroll
        for (int ni = 0; ni < 2; ++ni) {
            const int c = col0 + n_off + ni * 16 + l15;
            const float bv = bias[c];
#pragma unroll
            for (int r = 0; r < 4; ++r)
                Out[(size_t)(mrow + r) * DD + c] = acc[mi][ni][r] + bv;
        }
    }
}

// ---------------------------------------------------------------------------
// Kernel 4: residual add + RMSNorm. One block per token.
// ---------------------------------------------------------------------------
__global__ __launch_bounds__(256) void resid_rmsnorm(
    const float* __restrict__ proj, const float* __restrict__ hs,
    const float* __restrict__ scale, float* __restrict__ out)
{
    const int t = blockIdx.x;
    const int tid = threadIdx.x;
    const size_t base = (size_t)t * DD + tid * 4;

    const float4 p4 = *(const float4*)(proj + base);
    const float4 h4 = *(const float4*)(hs + base);
    float x0 = p4.x + h4.x, x1 = p4.y + h4.y, x2 = p4.z + h4.z, x3 = p4.w + h4.w;
    float ss = x0 * x0 + x1 * x1 + x2 * x2 + x3 * x3;

#pragma unroll
    for (int off = 1; off < 64; off <<= 1) ss += __shfl_xor(ss, off);

    __shared__ float wsum[4];
    if ((tid & 63) == 0) wsum[tid >> 6] = ss;
    __syncthreads();
    const float total = wsum[0] + wsum[1] + wsum[2] + wsum[3];
    const float inv = 1.f / (sqrtf(total * (1.f / DD)) + EPSF);

    const float4 s4 = *(const float4*)(scale + tid * 4);
    float4 o;
    o.x = s4.x * x0 * inv;
    o.y = s4.y * x1 * inv;
    o.z = s4.z * x2 * inv;
    o.w = s4.w * x3 * inv;
    *(float4*)(out + base) = o;
}

// ---------------------------------------------------------------------------
extern "C" void kernel_launch(void* const* d_in, const int* in_sizes, int n_in,
                              void* d_out, int out_size, void* d_ws, size_t ws_size,
                              hipStream_t stream) {
    const float* hs    = (const float*)d_in[0];
    const float* sinp  = (const float*)d_in[1];
    const float* cosp  = (const float*)d_in[2];
    const float* wq    = (const float*)d_in[3];
    const float* wk    = (const float*)d_in[4];
    const float* wv    = (const float*)d_in[5];
    const float* wo    = (const float*)d_in[6];
    const float* bo    = (const float*)d_in[7];
    const float* scale = (const float*)d_in[8];
    float* out = (float*)d_out;

    unsigned char* wsb = (unsigned char*)d_ws;
    const size_t MAT = (size_t)BB * SS * DD;
    const size_t WN  = (size_t)DD * DD;
    ushort* Abf = (ushort*)wsb;           // contiguous: Abf, Wqb, Wkb, Wvb, Wob
    ushort* Wqb = Abf + MAT;
    ushort* Wkb = Wqb + WN;
    ushort* Wvb = Wkb + WN;
    ushort* Wob = Wvb + WN;
    ushort* Qb  = Wob + WN;
    ushort* Kb  = Qb + MAT;
    ushort* Vtb = Kb + MAT;
    ushort* ctxb = Vtb + MAT;
    float* proj = (float*)(ctxb + MAT);

    const int nconv4 = (int)((MAT + 4 * WN) / 4);    // 2M float4 groups
    conv_all<<<dim3(nconv4 / 256), 256, 0, stream>>>(hs, wq, wk, wv, wo, Abf);

    gemm_qkv_mfma<<<dim3(32, 24), 256, 0, stream>>>(Abf, Wqb, Wkb, Wvb,
                                                    sinp, cosp, Qb, Kb, Vtb);
    attn_mfma<<<dim3(32 * BB * HH), 256, 0, stream>>>(Qb, Kb, Vtb, ctxb);
    gemm_out_mfma<<<dim3(32, 16), 256, 0, stream>>>(ctxb, Wob, bo, proj);
    resid_rmsnorm<<<dim3(BB * SS), 256, 0, stream>>>(proj, hs, scale, out);
}

// Round 4
// 195.292 us; speedup vs baseline: 1.1180x; 1.0658x over previous
//
#include <hip/hip_runtime.h>
#include <cmath>

#define BB 2
#define SS 2048
#define DD 1024
#define HH 16
#define HDIM 64
#define KDIM 1024
#define EPSF 1e-8f
// 0.125 (1/sqrt(HD)) * log2(e), folded into Q at projection time
#define QSCALE 0.18033688f

typedef __attribute__((ext_vector_type(8))) short bf16x8;
typedef __attribute__((ext_vector_type(4))) float f32x4;
typedef __attribute__((ext_vector_type(16))) float f32x16;

__device__ __forceinline__ ushort f2bf(float x) {
    unsigned u = __builtin_bit_cast(unsigned, x);
    u += 0x7FFFu + ((u >> 16) & 1u);   // RNE
    return (ushort)(u >> 16);
}

// pack two fp32 -> bf16x2 (truncation, 1 v_perm): low = a, high = b
__device__ __forceinline__ unsigned pack_bf16_trunc(float a, float b) {
    return __builtin_amdgcn_perm(__builtin_bit_cast(unsigned, b),
                                 __builtin_bit_cast(unsigned, a), 0x07060302u);
}

// raw v_exp_f32 (2^x): skips OCML range-guard code
__device__ __forceinline__ float exp2_fast(float x) {
    float r;
    asm("v_exp_f32 %0, %1" : "=v"(r) : "v"(x));
    return r;
}

__device__ __forceinline__ void gload_lds16(const ushort* g, ushort* l) {
    __builtin_amdgcn_global_load_lds(
        (const __attribute__((address_space(1))) unsigned*)g,
        (__attribute__((address_space(3))) unsigned*)l, 16, 0, 0);
}

// ---------------------------------------------------------------------------
// Fused fp32->bf16 conversion for hs + 4 weights (dsts contiguous in ws).
// ---------------------------------------------------------------------------
__global__ __launch_bounds__(256) void conv_all(
    const float* __restrict__ hs, const float* __restrict__ wq,
    const float* __restrict__ wk, const float* __restrict__ wv,
    const float* __restrict__ wo, ushort* __restrict__ dst)
{
    const int i = blockIdx.x * 256 + threadIdx.x;   // float4 group index
    const int HS4 = (BB * SS * DD) / 4;             // 1048576
    const int W4 = (DD * DD) / 4;                   // 262144
    const float* src;
    int off;
    if (i < HS4) { src = hs; off = i; }
    else {
        const int j = i - HS4;
        const int seg = j / W4;
        off = j - seg * W4;
        src = (seg == 0) ? wq : (seg == 1) ? wk : (seg == 2) ? wv : wo;
    }
    const float4 v = ((const float4*)src)[off];
    ushort4 o;
    o.x = f2bf(v.x); o.y = f2bf(v.y); o.z = f2bf(v.z); o.w = f2bf(v.w);
    ((ushort4*)dst)[i] = o;
}

// ---------------------------------------------------------------------------
// Kernel 1: fused QKV projection, bf16 MFMA (m97 structure).
// Q pre-scaled by QSCALE so attention softmax is a bare exp2.
// Q,K -> (B,H,S,HD) bf16; V -> (B,H,HD,S) bf16 (transposed).
// ---------------------------------------------------------------------------
__global__ __launch_bounds__(256) void gemm_qkv_mfma(
    const ushort* __restrict__ A,
    const ushort* __restrict__ Wq, const ushort* __restrict__ Wk,
    const ushort* __restrict__ Wv,
    const float* __restrict__ sinp, const float* __restrict__ cosp,
    ushort* __restrict__ Qb, ushort* __restrict__ Kb, ushort* __restrict__ Vtb)
{
    const int cb = blockIdx.y;
    const int z = cb >> 3;
    const int col0 = (cb & 7) * 128;
    const ushort* W = (z == 0) ? Wq : (z == 1) ? Wk : Wv;
    ushort* O = (z == 0) ? Qb : (z == 1) ? Kb : Vtb;
    const int row0 = blockIdx.x * 128;
    const float qs = (z == 0) ? QSCALE : 1.0f;

    __shared__ __align__(16) ushort As[128 * 32];
    __shared__ __align__(16) ushort Bs[128 * 32];

    const int tid = threadIdx.x;
    const int w = tid >> 6, lane = tid & 63;
    const int quad = lane >> 4, l15 = lane & 15;
    const int m_off = (w >> 1) * 64, n_off = (w & 1) * 64;

    f32x4 acc[4][4] = {};

    for (int k0 = 0; k0 < KDIM; k0 += 32) {
#pragma unroll
        for (int it = 0; it < 2; ++it) {
            const int L = (it * 4 + w) * 64 + lane;
            const int r = L >> 2, c8 = (L & 3) * 8;
            gload_lds16(A + (size_t)(row0 + r) * KDIM + k0 + c8, &As[L * 8]);
            gload_lds16(W + (size_t)(col0 + r) * KDIM + k0 + c8, &Bs[L * 8]);
        }
        __syncthreads();
        bf16x8 af[4], bfr[4];
#pragma unroll
        for (int i = 0; i < 4; ++i) {
            af[i]  = *(const bf16x8*)&As[(m_off + i * 16 + l15) * 32 + quad * 8];
            bfr[i] = *(const bf16x8*)&Bs[(n_off + i * 16 + l15) * 32 + quad * 8];
        }
#pragma unroll
        for (int i = 0; i < 4; ++i)
#pragma unroll
            for (int j = 0; j < 4; ++j)
                acc[i][j] = __builtin_amdgcn_mfma_f32_16x16x32_bf16(
                    af[i], bfr[j], acc[i][j], 0, 0, 0);
        __syncthreads();
    }

    const int b = (row0 + m_off) / SS;
#pragma unroll
    for (int mi = 0; mi < 4; ++mi) {
        const int mrow = row0 + m_off + mi * 16 + quad * 4;
#pragma unroll
        for (int ni = 0; ni < 4; ++ni) {
            const int c = col0 + n_off + ni * 16 + l15;
            const int h = c >> 6, e = c & 63;
            const int bh = b * HH + h;
            float outv[4];
#pragma unroll
            for (int r = 0; r < 4; ++r) {
                const int s = (mrow + r) & (SS - 1);
                const float sv = sinp[s * (HDIM / 2) + (e >> 1)];
                const float cv = cosp[s * (HDIM / 2) + (e >> 1)];
                const float v = acc[mi][ni][r];
                const float vp = __shfl_xor(v, 1);
                outv[r] = ((l15 & 1) ? (v * cv + vp * sv) : (v * cv - vp * sv)) * qs;
            }
            if (z < 2) {
#pragma unroll
                for (int r = 0; r < 4; ++r) {
                    const int s = (mrow + r) & (SS - 1);
                    const ushort mine = f2bf(outv[r]);
                    const ushort part = (ushort)__shfl_xor((int)mine, 1);
                    if (!(l15 & 1))
                        *(unsigned*)(O + ((size_t)(bh * SS + s)) * HDIM + e) =
                            (unsigned)mine | ((unsigned)part << 16);
                }
            } else {
                ushort4 pk;
                pk.x = f2bf(outv[0]); pk.y = f2bf(outv[1]);
                pk.z = f2bf(outv[2]); pk.w = f2bf(outv[3]);
                const int s0 = mrow & (SS - 1);
                *(ushort4*)(O + ((size_t)(bh * HDIM + e)) * SS + s0) = pk;
            }
        }
    }
}

// ---------------------------------------------------------------------------
// Kernel 2: flash attention, 32x32x16 bf16 MFMA, S^T formulation, in-block
// key-split, XOR-swizzled LDS, single-barrier ping-pong double buffer.
// Round-change vs 61.0us version:
//   * TWO q-subtiles per wave (64 q/wave, 128 q/block, grid 512): the kf/vf
//     LDS reads and the K/V staging are SHARED across both q-subtiles, so
//     LDS reads per MFMA halve (was 1:1, now 1:2), staging bytes and
//     barriers per output element halve. Residual bank-conflict count
//     (exactly 4 cy per ds_read_b128) identified as the structural b128
//     tax (m134: 12 cy vs 8 ideal) -- not fixable by 16B-granular swizzle,
//     so reduce READ COUNT instead.
//   * __launch_bounds__(256,2): cap VGPR at 256 (cacc=64, qf=32 regs).
//   * Merge epilogue runs two sequential qs-passes so scratch fits in kvb.
// ---------------------------------------------------------------------------
__global__ __launch_bounds__(256, 2) void attn_mfma(
    const ushort* __restrict__ Qb, const ushort* __restrict__ Kb,
    const ushort* __restrict__ Vtb, ushort* __restrict__ ctx)
{
    // XCD swizzle: grid 512 = 8 XCDs x 64; wg&7 = xcd, contiguous lin chunk
    // per XCD => 4 heads per XCD (2 MB K/V, L2-resident; verified R2).
    const int wg  = blockIdx.x;
    const int lin = (wg & 7) * 64 + (wg >> 3);
    const int bh   = lin >> 4;          // 0..31
    const int qblk = lin & 15;          // 0..15 (128 q each)
    const int b = bh / HH, h = bh % HH;
    const int q0 = qblk * 128;
    const int tid = threadIdx.x;
    const int w = tid >> 6;
    const int lane = tid & 63;
    const int l31 = lane & 31;
    const int g = lane >> 5;
    const int strip = w >> 1;     // q-strip (64 q): waves {0,1} -> 0, {2,3} -> 1
    const int phase = w & 1;      // key phase: low/high 32 keys of the tile

    // [buf][K=0/V=1][hf][row][32] ; K: hf = d-half, row = key (0..63)
    //                              V: hf = key-half, row = d (0..63). 32 KB.
    __shared__ __align__(16) ushort kvb[2][2][2][64][32];

    const ushort* Qh = Qb  + (size_t)bh * SS * HDIM;
    const ushort* Kh = Kb  + (size_t)bh * SS * HDIM;
    const ushort* Vh = Vtb + (size_t)bh * HDIM * SS;

    // Q B-fragments for both q-subtiles (n = l31 = q-row, k = d)
    const int qrowA = q0 + strip * 64 + l31;        // qs = 0
    const int qrowB = qrowA + 32;                   // qs = 1
    bf16x8 qf[2][4];
#pragma unroll
    for (int ks = 0; ks < 4; ++ks) {
        qf[0][ks] = *(const bf16x8*)(Qh + (size_t)qrowA * HDIM + ks * 16 + g * 8);
        qf[1][ks] = *(const bf16x8*)(Qh + (size_t)qrowB * HDIM + ks * 16 + g * 8);
    }

    f32x16 cacc[2][2] = {};        // [qs][dt]
    float ls0a = 0.f, ls0b = 0.f, ls1a = 0.f, ls1b = 0.f;

    const int lr = lane >> 2;               // staging row-in-16
    const int c16 = lane & 3;               // 16-B chunk index
    const int lc = c16 * 8;                 // ushort col in global
    const int swc = (c16 ^ ((lr >> 1) & 3)) * 8;   // swizzled LDS chunk
    const int srow = w * 16 + lr;           // staging row 0..63
    const int rsw = (l31 >> 1) & 3;         // read-side swizzle term

    // staging registers for ONE 64-key tile (K: 2 d-halves, V: 2 key-halves)
    uint4 rk0, rk1, rv0, rv1;

#define LOAD_STAGE(K0)                                                        \
    do {                                                                      \
        const ushort* Kp = Kh + (size_t)((K0) + srow) * HDIM + lc;            \
        const ushort* Vp = Vh + (size_t)srow * SS + (K0) + lc;                \
        rk0 = *(const uint4*)(Kp);                                            \
        rk1 = *(const uint4*)(Kp + 32);                                       \
        rv0 = *(const uint4*)(Vp);                                            \
        rv1 = *(const uint4*)(Vp + 32);                                       \
    } while (0)

#define WRITE_STAGE(bufi)                                                     \
    do {                                                                      \
        *(uint4*)&kvb[bufi][0][0][srow][swc] = rk0;                           \
        *(uint4*)&kvb[bufi][0][1][srow][swc] = rk1;                           \
        *(uint4*)&kvb[bufi][1][0][srow][swc] = rv0;                           \
        *(uint4*)&kvb[bufi][1][1][srow][swc] = rv1;                           \
    } while (0)

    const int NT = SS / 64;                 // 32 tiles

    LOAD_STAGE(0);
    WRITE_STAGE(0);
    LOAD_STAGE(64);                         // regs now hold tile 1

    for (int t = 0; t < NT; ++t) {
        __syncthreads();      // buf[t&1] writes visible; buf[t&1^1] readers done
        const int cur = t & 1;

        // ---- K fragment reads FIRST (so their lgkm wait excludes writes) ----
        bf16x8 kf[4];
#pragma unroll
        for (int ks = 0; ks < 4; ++ks)
            kf[ks] = *(const bf16x8*)&kvb[cur][0][ks >> 1]
                [phase * 32 + l31][(((ks & 1) * 2 + g) ^ rsw) * 8];

        // ---- overlap: write tile t+1 into the other buffer, prefetch t+2 ----
        if (t + 1 < NT) WRITE_STAGE(cur ^ 1);
        if (t + 2 < NT) LOAD_STAGE((t + 2) * 64);

        // ---- S^T = K . Q^T : two independent 4-chains (one per q-subtile) ----
        f32x16 sacc0 = {}, sacc1 = {};
        __builtin_amdgcn_s_setprio(1);
#pragma unroll
        for (int ks = 0; ks < 4; ++ks) {
            sacc0 = __builtin_amdgcn_mfma_f32_32x32x16_bf16(
                kf[ks], qf[0][ks], sacc0, 0, 0, 0);
            sacc1 = __builtin_amdgcn_mfma_f32_32x32x16_bf16(
                kf[ks], qf[1][ks], sacc1, 0, 0, 0);
        }
        __builtin_amdgcn_s_setprio(0);

        // ---- shift-free softmax + pack P^T pairs (2 partial chains/qs) ----
        unsigned pk[2][8];
#pragma unroll
        for (int i = 0; i < 8; ++i) {
            const float pa0 = exp2_fast(sacc0[2 * i]);
            const float pb0 = exp2_fast(sacc0[2 * i + 1]);
            const float pa1 = exp2_fast(sacc1[2 * i]);
            const float pb1 = exp2_fast(sacc1[2 * i + 1]);
            if (i & 1) { ls0b += pa0 + pb0; ls1b += pa1 + pb1; }
            else       { ls0a += pa0 + pb0; ls1a += pa1 + pb1; }
            pk[0][i] = pack_bf16_trunc(pa0, pb0);
            pk[1][i] = pack_bf16_trunc(pa1, pb1);
        }

        // ---- ctx^T += V^T . P^T : each vf read feeds BOTH q-subtiles ----
#pragma unroll
        for (int ks = 0; ks < 2; ++ks) {
            const int bq = ks * 4;
            unsigned a00 = pk[0][bq + 0], a01 = pk[0][bq + 1];
            unsigned b00 = pk[0][bq + 2], b01 = pk[0][bq + 3];
            unsigned a10 = pk[1][bq + 0], a11 = pk[1][bq + 1];
            unsigned b10 = pk[1][bq + 2], b11 = pk[1][bq + 3];
            asm("v_permlane32_swap_b32 %0, %1" : "+v"(a00), "+v"(b00));
            asm("v_permlane32_swap_b32 %0, %1" : "+v"(a01), "+v"(b01));
            asm("v_permlane32_swap_b32 %0, %1" : "+v"(a10), "+v"(b10));
            asm("v_permlane32_swap_b32 %0, %1" : "+v"(a11), "+v"(b11));
            union { unsigned u[4]; bf16x8 v; } pf0, pf1;
            pf0.u[0] = a00; pf0.u[1] = a01; pf0.u[2] = b00; pf0.u[3] = b01;
            pf1.u[0] = a10; pf1.u[1] = a11; pf1.u[2] = b10; pf1.u[3] = b11;
            __builtin_amdgcn_s_setprio(1);
#pragma unroll
            for (int dt = 0; dt < 2; ++dt) {
                const bf16x8 vf = *(const bf16x8*)&kvb[cur][1][phase]
                    [dt * 32 + l31][((ks * 2 + g) ^ rsw) * 8];
                cacc[0][dt] = __builtin_amdgcn_mfma_f32_32x32x16_bf16(
                    vf, pf0.v, cacc[0][dt], 0, 0, 0);
                cacc[1][dt] = __builtin_amdgcn_mfma_f32_32x32x16_bf16(
                    vf, pf1.v, cacc[1][dt], 0, 0, 0);
            }
            __builtin_amdgcn_s_setprio(0);
        }
    }

    float lsq[2];
    lsq[0] = ls0a + ls0b;
    lsq[1] = ls1a + ls1b;
    // within-wave: partner half holds the other half of each 32-key chunk
    lsq[0] += __shfl_xor(lsq[0], 32);
    lsq[1] += __shfl_xor(lsq[1], 32);

    // ---- strip merge, two sequential qs-passes (scratch fits in kvb) ----
    float* mlds = (float*)kvb;
    const int mbase = strip * 2112 + lane * 33;   // stride 33: conflict-free
#pragma unroll
    for (int qs = 0; qs < 2; ++qs) {
        __syncthreads();
        if (phase == 1) {
#pragma unroll
            for (int dt = 0; dt < 2; ++dt)
#pragma unroll
                for (int i = 0; i < 16; ++i)
                    mlds[mbase + dt * 16 + i] = cacc[qs][dt][i];
            mlds[mbase + 32] = lsq[qs];
        }
        __syncthreads();
        if (phase == 0) {
            f32x16 cf[2];
#pragma unroll
            for (int dt = 0; dt < 2; ++dt)
#pragma unroll
                for (int i = 0; i < 16; ++i)
                    cf[dt][i] = cacc[qs][dt][i] + mlds[mbase + dt * 16 + i];
            const float inv = 1.f / (lsq[qs] + mlds[mbase + 32]);

            // epilogue: C-layout col = l31 = q, row = (r&3)+8*(r>>2)+4g
            const int qrow = (qs == 0) ? qrowA : qrowB;
            const size_t obase = ((size_t)(b * SS + qrow)) * DD + h * HDIM;
#pragma unroll
            for (int dt = 0; dt < 2; ++dt)
#pragma unroll
                for (int tt = 0; tt < 4; ++tt) {
                    ushort4 o;
                    o.x = f2bf(cf[dt][tt * 4 + 0] * inv);
                    o.y = f2bf(cf[dt][tt * 4 + 1] * inv);
                    o.z = f2bf(cf[dt][tt * 4 + 2] * inv);
                    o.w = f2bf(cf[dt][tt * 4 + 3] * inv);
                    *(ushort4*)(ctx + obase + dt * 32 + tt * 8 + g * 4) = o;
                }
        }
    }
#undef LOAD_STAGE
#undef WRITE_STAGE
}

// ---------------------------------------------------------------------------
// Kernel 3: output projection, bf16 MFMA, 128x64 tile (512 blocks = 2/CU),
// + bias, fp32 out (B*S, D).
// ---------------------------------------------------------------------------
__global__ __launch_bounds__(256) void gemm_out_mfma(
    const ushort* __restrict__ A, const ushort* __restrict__ W,
    const float* __restrict__ bias, float* __restrict__ Out)
{
    const int row0 = blockIdx.x * 128;
    const int col0 = blockIdx.y * 64;

    __shared__ __align__(16) ushort As[128 * 32];
    __shared__ __align__(16) ushort Bs[64 * 32];

    const int tid = threadIdx.x;
    const int w = tid >> 6, lane = tid & 63;
    const int quad = lane >> 4, l15 = lane & 15;
    const int m_off = (w >> 1) * 64, n_off = (w & 1) * 32;

    f32x4 acc[4][2] = {};

    for (int k0 = 0; k0 < KDIM; k0 += 32) {
#pragma unroll
        for (int it = 0; it < 2; ++it) {
            const int L = (it * 4 + w) * 64 + lane;
            const int r = L >> 2, c8 = (L & 3) * 8;
            gload_lds16(A + (size_t)(row0 + r) * KDIM + k0 + c8, &As[L * 8]);
        }
        {
            const int L = w * 64 + lane;
            const int r = L >> 2, c8 = (L & 3) * 8;
            gload_lds16(W + (size_t)(col0 + r) * KDIM + k0 + c8, &Bs[L * 8]);
        }
        __syncthreads();
        bf16x8 af[4], bfr[2];
#pragma unroll
        for (int i = 0; i < 4; ++i)
            af[i] = *(const bf16x8*)&As[(m_off + i * 16 + l15) * 32 + quad * 8];
#pragma unroll
        for (int j = 0; j < 2; ++j)
            bfr[j] = *(const bf16x8*)&Bs[(n_off + j * 16 + l15) * 32 + quad * 8];
#pragma unroll
        for (int i = 0; i < 4; ++i)
#pragma unroll
            for (int j = 0; j < 2; ++j)
                acc[i][j] = __builtin_amdgcn_mfma_f32_16x16x32_bf16(
                    af[i], bfr[j], acc[i][j], 0, 0, 0);
        __syncthreads();
    }

#pragma unroll
    for (int mi = 0; mi < 4; ++mi) {
        const int mrow = row0 + m_off + mi * 16 + quad * 4;
#pragma unroll
        for (int ni = 0; ni < 2; ++ni) {
            const int c = col0 + n_off + ni * 16 + l15;
            const float bv = bias[c];
#pragma unroll
            for (int r = 0; r < 4; ++r)
                Out[(size_t)(mrow + r) * DD + c] = acc[mi][ni][r] + bv;
        }
    }
}

// ---------------------------------------------------------------------------
// Kernel 4: residual add + RMSNorm. One block per token.
// ---------------------------------------------------------------------------
__global__ __launch_bounds__(256) void resid_rmsnorm(
    const float* __restrict__ proj, const float* __restrict__ hs,
    const float* __restrict__ scale, float* __restrict__ out)
{
    const int t = blockIdx.x;
    const int tid = threadIdx.x;
    const size_t base = (size_t)t * DD + tid * 4;

    const float4 p4 = *(const float4*)(proj + base);
    const float4 h4 = *(const float4*)(hs + base);
    float x0 = p4.x + h4.x, x1 = p4.y + h4.y, x2 = p4.z + h4.z, x3 = p4.w + h4.w;
    float ss = x0 * x0 + x1 * x1 + x2 * x2 + x3 * x3;

#pragma unroll
    for (int off = 1; off < 64; off <<= 1) ss += __shfl_xor(ss, off);

    __shared__ float wsum[4];
    if ((tid & 63) == 0) wsum[tid >> 6] = ss;
    __syncthreads();
    const float total = wsum[0] + wsum[1] + wsum[2] + wsum[3];
    const float inv = 1.f / (sqrtf(total * (1.f / DD)) + EPSF);

    const float4 s4 = *(const float4*)(scale + tid * 4);
    float4 o;
    o.x = s4.x * x0 * inv;
    o.y = s4.y * x1 * inv;
    o.z = s4.z * x2 * inv;
    o.w = s4.w * x3 * inv;
    *(float4*)(out + base) = o;
}

// ---------------------------------------------------------------------------
extern "C" void kernel_launch(void* const* d_in, const int* in_sizes, int n_in,
                              void* d_out, int out_size, void* d_ws, size_t ws_size,
                              hipStream_t stream) {
    const float* hs    = (const float*)d_in[0];
    const float* sinp  = (const float*)d_in[1];
    const float* cosp  = (const float*)d_in[2];
    const float* wq    = (const float*)d_in[3];
    const float* wk    = (const float*)d_in[4];
    const float* wv    = (const float*)d_in[5];
    const float* wo    = (const float*)d_in[6];
    const float* bo    = (const float*)d_in[7];
    const float* scale = (const float*)d_in[8];
    float* out = (float*)d_out;

    unsigned char* wsb = (unsigned char*)d_ws;
    const size_t MAT = (size_t)BB * SS * DD;
    const size_t WN  = (size_t)DD * DD;
    ushort* Abf = (ushort*)wsb;           // contiguous: Abf, Wqb, Wkb, Wvb, Wob
    ushort* Wqb = Abf + MAT;
    ushort* Wkb = Wqb + WN;
    ushort* Wvb = Wkb + WN;
    ushort* Wob = Wvb + WN;
    ushort* Qb  = Wob + WN;
    ushort* Kb  = Qb + MAT;
    ushort* Vtb = Kb + MAT;
    ushort* ctxb = Vtb + MAT;
    float* proj = (float*)(ctxb + MAT);

    const int nconv4 = (int)((MAT + 4 * WN) / 4);    // 2M float4 groups
    conv_all<<<dim3(nconv4 / 256), 256, 0, stream>>>(hs, wq, wk, wv, wo, Abf);

    gemm_qkv_mfma<<<dim3(32, 24), 256, 0, stream>>>(Abf, Wqb, Wkb, Wvb,
                                                    sinp, cosp, Qb, Kb, Vtb);
    attn_mfma<<<dim3(512), 256, 0, stream>>>(Qb, Kb, Vtb, ctxb);
    gemm_out_mfma<<<dim3(32, 16), 256, 0, stream>>>(ctxb, Wob, bo, proj);
    resid_rmsnorm<<<dim3(BB * SS), 256, 0, stream>>>(proj, hs, scale, out);
}